// Round 7
// baseline (206.508 us; speedup 1.0000x reference)
//
#include <hip/hip_runtime.h>

#define HH 256
#define WW 256
#define HWPX 65536
#define BB 8
#define KK 21
#define CC 32

typedef _Float16 half2v __attribute__((ext_vector_type(2)));
union F4H { float4 f4; half2v h[4]; };

// ---------------- kernel 1 (fused): T + |q|^2 + planar f16 pack, 2 px/thread ----------------
// fpk layout: plane j (8 channels), plane stride BB*HWPX float4s; within plane
// [global pixel idx] -> 16 B, lane-contiguous.
__global__ __launch_bounds__(256) void prep(const float* __restrict__ cls,
                                            const float* __restrict__ feat,
                                            float4* __restrict__ fpk,
                                            float2* __restrict__ TN) {
    const int tid = blockIdx.x * 256 + threadIdx.x;   // 0..262143
    const int p2 = tid * 2;                           // global pixel idx (b*HWPX+p)
    const int b = p2 >> 16;
    const int p = p2 & (HWPX - 1);

    // T = sum_k S, 2 px at once (float2 loads, fully unrolled: 21 independent loads)
    const float* cbase = cls + (size_t)b * KK * HWPX + p;
    float sx = 0.f, sy = 0.f;
#pragma unroll
    for (int k = 0; k < KK; ++k) {
        float2 c = *(const float2*)(cbase + (size_t)k * HWPX);
        sx += c.x; sy += c.y;
    }

    const float* src = feat + (size_t)b * CC * HWPX + p;
    float nq0 = 0.f, nq1 = 0.f;
#pragma unroll 1   // runtime plane loop: only 8 channel loads in flight (round-3/6 hoist lesson)
    for (int j = 0; j < 4; ++j) {
        float2 ch[8];
#pragma unroll
        for (int c = 0; c < 8; ++c)
            ch[c] = *(const float2*)(src + (size_t)(j * 8 + c) * HWPX);
        F4H u0, u1;
#pragma unroll
        for (int k = 0; k < 4; ++k) {
            u0.h[k] = __builtin_bit_cast(half2v, __builtin_amdgcn_cvt_pkrtz(ch[2 * k].x, ch[2 * k + 1].x));
            nq0 = __builtin_amdgcn_fdot2(u0.h[k], u0.h[k], nq0, false);
            u1.h[k] = __builtin_bit_cast(half2v, __builtin_amdgcn_cvt_pkrtz(ch[2 * k].y, ch[2 * k + 1].y));
            nq1 = __builtin_amdgcn_fdot2(u1.h[k], u1.h[k], nq1, false);
        }
        fpk[(size_t)j * (BB * HWPX) + p2]     = u0.f4;
        fpk[(size_t)j * (BB * HWPX) + p2 + 1] = u1.f4;
    }
    TN[p2]     = make_float2(sx, nq0);
    TN[p2 + 1] = make_float2(sy, nq1);
}

// ---------------- kernel 2 (hot, fused): affinity + per-(b,j) reduction ----------------
// w(p,q) = exp(-off^2/16 - (|p|^2+|q|^2-2 p.q)); acc telescopes, w = exp2(2*log2e*acc).
// Epilogue: stage V/deg in LDS, reduce against cls in-block, 42 atomics/block.
__global__ __launch_bounds__(256) void affinity5(const float4* __restrict__ fpk,
                                                 const float2* __restrict__ TN,
                                                 const float* __restrict__ cls,
                                                 float* __restrict__ numer,
                                                 float* __restrict__ denom) {
    __shared__ float smV[1024], smD[1024];
    __shared__ float pN[4][22], pD[4][22];

    // XCD swizzle: L%8 = batch so each XCD's round-robin share is one batch (~4.7 MB, L2-resident)
    const int L  = blockIdx.x;            // 0..511
    const int b  = L & 7;
    const int t  = L >> 3;
    const int by = t & 15;
    const int bx = t >> 4;                // 0..3
    const int lane = threadIdx.x & 63;
    const int wid  = threadIdx.x >> 6;
    const int gx  = bx * 64 + lane;
    const int gy0 = by * 16 + wid * 4;    // owns rows gy0..gy0+3

    const size_t bofs = (size_t)b * HWPX;
    const float4* fb0 = fpk + bofs;
    const float4* fb1 = fpk + (size_t)1 * BB * HWPX + bofs;
    const float4* fb2 = fpk + (size_t)2 * BB * HWPX + bofs;
    const float4* fb3 = fpk + (size_t)3 * BB * HWPX + bofs;
    const float2* tnb = TN + bofs;

    F4H fp[4][4];
    float np_[4];
#pragma unroll
    for (int py = 0; py < 4; ++py) {
        const int pp = ((gy0 + py) << 8) | gx;
        fp[py][0].f4 = fb0[pp];
        fp[py][1].f4 = fb1[pp];
        fp[py][2].f4 = fb2[pp];
        fp[py][3].f4 = fb3[pp];
        np_[py] = tnb[pp].y;
    }

    float degacc[4] = {0.f, 0.f, 0.f, 0.f};
    float vacc[4]   = {0.f, 0.f, 0.f, 0.f};

#pragma unroll 1   // runtime row loop: caps load-hoisting window (round-3 spill lesson)
    for (int dyi = 0; dyi < 12; ++dyi) {
        const int ny = gy0 + dyi - 4;               // neighbor row, same for all py
        if ((unsigned)ny >= HH) continue;           // uniform: OOB row contributes 0
        const int rowq = ny << 8;

        int dy2[4];
        float base[4];
#pragma unroll
        for (int py = 0; py < 4; ++py) {
            const int d = dyi - 4 - py;             // uniform
            dy2[py] = d * d;
            base[py] = fmaf(-0.03125f, (float)dy2[py], -0.5f * np_[py]);
        }
        const int mind = min(min(dy2[0], dy2[1]), min(dy2[2], dy2[3]));

#pragma unroll 3
        for (int dxi = 0; dxi < 9; ++dxi) {
            const int dx = dxi - 4;                 // uniform
            const int dx2 = dx * dx;
            if (mind + dx2 >= 25) continue;         // uniform: no py uses this column

            const int gx2 = gx + dx;
            const bool vx = (unsigned)gx2 < WW;     // per-lane x bound
            const int q = rowq | min(max(gx2, 0), WW - 1);

            F4H nb0, nb1, nb2, nb3;
            nb0.f4 = fb0[q];
            nb1.f4 = fb1[q];
            nb2.f4 = fb2[q];
            nb3.f4 = fb3[q];
            const float2 tq = tnb[q];
            const float cdx = (float)dx2 * -0.03125f;

#pragma unroll
            for (int py = 0; py < 4; ++py) {
                if (dy2[py] + dx2 < 25) {           // uniform circle test
                    float acc = fmaf(-0.5f, tq.y, base[py] + cdx);
#pragma unroll
                    for (int k = 0; k < 4; ++k) {
                        acc = __builtin_amdgcn_fdot2(fp[py][0].h[k], nb0.h[k], acc, false);
                        acc = __builtin_amdgcn_fdot2(fp[py][1].h[k], nb1.h[k], acc, false);
                        acc = __builtin_amdgcn_fdot2(fp[py][2].h[k], nb2.h[k], acc, false);
                        acc = __builtin_amdgcn_fdot2(fp[py][3].h[k], nb3.h[k], acc, false);
                    }
                    float w = __builtin_exp2f(acc * 2.8853900817779268f);  // exp(2*acc)
                    w = vx ? w : 0.f;
                    degacc[py] += w;
                    vacc[py] = fmaf(w, tq.x, vacc[py]);
                }
            }
        }
    }

    // ---- fused reduction epilogue ----
#pragma unroll
    for (int py = 0; py < 4; ++py) {
        const int li = ((wid * 4 + py) << 6) | lane;   // local row-major 16x64
        smV[li] = vacc[py];
        smD[li] = degacc[py];
    }
    __syncthreads();

    // each thread reduces 4 consecutive local px (float4-coalesced cls reads)
    const int li0 = threadIdx.x * 4;
    const int lr  = li0 >> 6;
    const int lc  = li0 & 63;
    const int gp  = ((by * 16 + lr) << 8) | (bx * 64 + lc);
    const float4 v4 = *(const float4*)&smV[li0];
    const float4 d4 = *(const float4*)&smD[li0];
    const float* clsb = cls + (size_t)b * KK * HWPX + gp;

    float accN[KK], accD[KK];
#pragma unroll 7   // 7 loads in flight; full 21 would be fine but keep hoist window bounded
    for (int j = 0; j < KK; ++j) {
        float4 s4 = *(const float4*)(clsb + (size_t)j * HWPX);
        float n = s4.x * v4.x;   n = fmaf(s4.y, v4.y, n);
        n = fmaf(s4.z, v4.z, n); n = fmaf(s4.w, v4.w, n);
        float d = s4.x * d4.x;   d = fmaf(s4.y, d4.y, d);
        d = fmaf(s4.z, d4.z, d); d = fmaf(s4.w, d4.w, d);
        accN[j] = n; accD[j] = d;
    }

#pragma unroll
    for (int j = 0; j < KK; ++j) {
        float n = accN[j], d = accD[j];
#pragma unroll
        for (int off = 32; off > 0; off >>= 1) {
            n += __shfl_down(n, off);
            d += __shfl_down(d, off);
        }
        if (lane == 0) { pN[wid][j] = n; pD[wid][j] = d; }
    }
    __syncthreads();
    if (threadIdx.x < 2 * KK) {
        int half = threadIdx.x / KK;
        int j = threadIdx.x - half * KK;
        float acc = half ? (pD[0][j] + pD[1][j] + pD[2][j] + pD[3][j])
                         : (pN[0][j] + pN[1][j] + pN[2][j] + pN[3][j]);
        float* dst = half ? denom : numer;
        atomicAdd(&dst[b * KK + j], acc);
    }
}

// ---------------- kernel 3: out = sum_{b,j} numer/denom ----------------
__global__ __launch_bounds__(256) void finalize(const float* __restrict__ numer,
                                                const float* __restrict__ denom,
                                                float* __restrict__ out) {
    __shared__ float sm[4];
    int i = threadIdx.x;
    float r = 0.f;
    if (i < BB * KK) r = numer[i] / denom[i];
#pragma unroll
    for (int off = 32; off > 0; off >>= 1) r += __shfl_down(r, off);
    if ((i & 63) == 0) sm[i >> 6] = r;
    __syncthreads();
    if (i == 0) out[0] = sm[0] + sm[1] + sm[2] + sm[3];
}

extern "C" void kernel_launch(void* const* d_in, const int* in_sizes, int n_in,
                              void* d_out, int out_size, void* d_ws, size_t ws_size,
                              hipStream_t stream) {
    const float* cls  = (const float*)d_in[0];  // [B,K,H,W]
    const float* feat = (const float*)d_in[1];  // [B,C,H,W]
    float* out = (float*)d_out;

    const size_t BHW = (size_t)BB * HWPX;
    // fpk (33.5 MB) | TN (4.2 MB) | numer | denom
    float4* fpk   = (float4*)d_ws;
    float2* TN    = (float2*)((char*)d_ws + BHW * 64);
    float*  numer = (float*)((char*)TN + BHW * 8);
    float*  denom = numer + BB * KK;

    (void)hipMemsetAsync(numer, 0, 2 * BB * KK * sizeof(float), stream);
    prep<<<dim3(BHW / 512), dim3(256), 0, stream>>>(cls, feat, fpk, TN);
    affinity5<<<dim3(512), dim3(256), 0, stream>>>(fpk, TN, cls, numer, denom);
    finalize<<<dim3(1), dim3(256), 0, stream>>>(numer, denom, out);
}